// Round 2
// baseline (1243.887 us; speedup 1.0000x reference)
//
#include <hip/hip_runtime.h>
#include <hip/hip_bf16.h>
#include <stdint.h>

// Problem constants
// B=8192, H_IN=4096, H_OUT=4096, K=4, R=8
// K' = 4096 + 32 = 4128 (129 K-tiles of 32)

typedef __attribute__((ext_vector_type(4))) float f32x4;
typedef __attribute__((ext_vector_type(8))) short bf16x8;
typedef __attribute__((ext_vector_type(4))) unsigned short u16x4;
typedef __attribute__((ext_vector_type(8))) unsigned short u16x8;

#define KPRIME 4128

__device__ __forceinline__ unsigned short f2bf(float f) {
    union { float f; uint32_t u; } v; v.f = f;
    uint32_t r = (v.u + 0x7FFFu + ((v.u >> 16) & 1u)) >> 16;
    return (unsigned short)r;
}

__device__ __forceinline__ void gload16(const void* g, void* l) {
    __builtin_amdgcn_global_load_lds(
        (const __attribute__((address_space(1))) void*)g,
        (__attribute__((address_space(3))) void*)l,
        16, 0, 0);
}

// ---------------------------------------------------------------------------
// K1: build W' [4096][4128] bf16: cols 0..4095 = bf16(W), cols 4096..4127 =
// bf16(scaling[o] * qb[k][o][r]) with kr = k*8+r.
// ---------------------------------------------------------------------------
__global__ void build_w(const float* __restrict__ W, const float* __restrict__ qb,
                        const float* __restrict__ scaling,
                        unsigned short* __restrict__ Wp) {
    int o = blockIdx.x;       // 4096
    int t = threadIdx.x;      // 256
    const size_t wrow = (size_t)o * 4096;
    const size_t prow = (size_t)o * KPRIME;
#pragma unroll
    for (int i = 0; i < 4; ++i) {
        int h = (i * 256 + t) * 4;
        f32x4 v = *(const f32x4*)&W[wrow + h];
        u16x4 b;
        b.x = f2bf(v.x); b.y = f2bf(v.y); b.z = f2bf(v.z); b.w = f2bf(v.w);
        *(u16x4*)&Wp[prow + h] = b;
    }
    if (t < 32) {
        int k = t >> 3, r = t & 7;
        float v = scaling[o] * qb[((size_t)k * 4096 + o) * 8 + r];
        Wp[prow + 4096 + t] = f2bf(v);
    }
}

// ---------------------------------------------------------------------------
// K2a: convert x [8192][4096] f32 -> x' cols 0..4095 bf16 (row stride 4128)
// ---------------------------------------------------------------------------
__global__ void conv_x(const float* __restrict__ X, unsigned short* __restrict__ Xp) {
    size_t idx = ((size_t)blockIdx.x * 256 + threadIdx.x) * 8;  // 16384 blocks
    size_t b = idx >> 12;
    size_t h = idx & 4095;
    f32x4 v0 = *(const f32x4*)&X[idx];
    f32x4 v1 = *(const f32x4*)&X[idx + 4];
    u16x8 o;
    o.s0 = f2bf(v0.x); o.s1 = f2bf(v0.y); o.s2 = f2bf(v0.z); o.s3 = f2bf(v0.w);
    o.s4 = f2bf(v1.x); o.s5 = f2bf(v1.y); o.s6 = f2bf(v1.z); o.s7 = f2bf(v1.w);
    *(u16x8*)&Xp[b * KPRIME + h] = o;
}

// ---------------------------------------------------------------------------
// K2b: a[b][kr] = x[b,:].qa[kr,:]; x' tail col 4096+kr = bf16(a * tkw[b][kr>>3])
// Block = 256 threads = 16 rows x 16 col-splits (256 h each). qa (512KB) gets
// 16-way intra-block reuse (L1/L2).
// ---------------------------------------------------------------------------
__global__ void calc_a(const float* __restrict__ X, const float* __restrict__ qa,
                       const float* __restrict__ tkw, unsigned short* __restrict__ Xp) {
    int t = threadIdx.x;
    int rb = t >> 4, tc = t & 15;
    int row = blockIdx.x * 16 + rb;
    float acc[32];
#pragma unroll
    for (int i = 0; i < 32; ++i) acc[i] = 0.f;
    const float* xr = X + (size_t)row * 4096 + tc * 256;
    const float* qr = qa + tc * 256;
    for (int hb = 0; hb < 64; ++hb) {
        f32x4 xv = *(const f32x4*)&xr[hb * 4];
#pragma unroll
        for (int kr = 0; kr < 32; ++kr) {
            f32x4 qv = *(const f32x4*)&qr[(size_t)kr * 4096 + hb * 4];
            acc[kr] += xv.x * qv.x + xv.y * qv.y + xv.z * qv.z + xv.w * qv.w;
        }
    }
    float keep0 = 0.f, keep1 = 0.f;
#pragma unroll
    for (int kr = 0; kr < 32; ++kr) {
        float v = acc[kr];
        v += __shfl_xor(v, 1);
        v += __shfl_xor(v, 2);
        v += __shfl_xor(v, 4);
        v += __shfl_xor(v, 8);
        if (tc == (kr & 15)) { if (kr < 16) keep0 = v; else keep1 = v; }
    }
    // thread tc owns kr = tc and kr = tc+16
    float w0 = tkw[(size_t)row * 4 + (tc >> 3)];
    float w1 = tkw[(size_t)row * 4 + 2 + (tc >> 3)];
    Xp[(size_t)row * KPRIME + 4096 + tc]      = f2bf(keep0 * w0);
    Xp[(size_t)row * KPRIME + 4096 + 16 + tc] = f2bf(keep1 * w1);
}

// ---------------------------------------------------------------------------
// K3: GEMM out[8192][4096] f32 = x'[8192][4128] @ W'[4096][4128]^T  (bf16 MFMA)
// m97 structure: 128x128 tile, BK=32, 4 waves, global_load_lds w=16,
// 16x16x32 bf16 MFMA, 4x4 frags/wave, 2 barriers per K-step.
// ---------------------------------------------------------------------------
__global__ __launch_bounds__(256) void gemm_k(const unsigned short* __restrict__ A,
                                              const unsigned short* __restrict__ Bw,
                                              float* __restrict__ C) {
    __shared__ unsigned short As[128 * 32];
    __shared__ unsigned short Bs[128 * 32];

    int wg = blockIdx.x;                       // 2048
    int swz = (wg & 7) * 256 + (wg >> 3);      // XCD swizzle (2048 % 8 == 0)
    int mt = swz >> 5;                         // 0..63
    int nt = swz & 31;                         // 0..31
    int m0 = mt * 128, n0 = nt * 128;

    int t = threadIdx.x;
    int lane = t & 63;
    int w = t >> 6;

    f32x4 acc[4][4];
#pragma unroll
    for (int i = 0; i < 4; ++i)
#pragma unroll
        for (int j = 0; j < 4; ++j)
            acc[i][j] = f32x4{0.f, 0.f, 0.f, 0.f};

    const int fm = lane & 15;
    const int kg = lane >> 4;
    const int wrow = (w >> 1) * 64;
    const int wcol = (w & 1) * 64;
    const int srow = lane >> 2;                // 0..15 within chunk
    const int skc = (lane & 3) * 8;            // ushort offset within BK

    for (int kt = 0; kt < 129; ++kt) {
        __syncthreads();
#pragma unroll
        for (int j = 0; j < 2; ++j) {
            int c = w + j * 4;                 // chunk 0..7 (16 rows each)
            int row = c * 16 + srow;
            gload16(&A[(size_t)(m0 + row) * KPRIME + kt * 32 + skc], &As[c * 512]);
            gload16(&Bw[(size_t)(n0 + row) * KPRIME + kt * 32 + skc], &Bs[c * 512]);
        }
        __syncthreads();

        bf16x8 af[4], bfr[4];
#pragma unroll
        for (int i = 0; i < 4; ++i) {
            af[i]  = *(const bf16x8*)&As[(wrow + i * 16 + fm) * 32 + kg * 8];
            bfr[i] = *(const bf16x8*)&Bs[(wcol + i * 16 + fm) * 32 + kg * 8];
        }
#pragma unroll
        for (int i = 0; i < 4; ++i)
#pragma unroll
            for (int j = 0; j < 4; ++j)
                acc[i][j] = __builtin_amdgcn_mfma_f32_16x16x32_bf16(af[i], bfr[j], acc[i][j], 0, 0, 0);
    }

    // Epilogue: C/D layout col = lane&15, row = (lane>>4)*4 + reg  [m89/m91]
#pragma unroll
    for (int i = 0; i < 4; ++i) {
        int r0 = m0 + wrow + i * 16 + kg * 4;
#pragma unroll
        for (int j = 0; j < 4; ++j) {
            int col = n0 + wcol + j * 16 + fm;
#pragma unroll
            for (int reg = 0; reg < 4; ++reg)
                C[(size_t)(r0 + reg) * 4096 + col] = acc[i][j][reg];
        }
    }
}

extern "C" void kernel_launch(void* const* d_in, const int* in_sizes, int n_in,
                              void* d_out, int out_size, void* d_ws, size_t ws_size,
                              hipStream_t stream) {
    const float* x   = (const float*)d_in[0];   // [8192][4096]
    const float* tkw = (const float*)d_in[1];   // [8192][4]
    const float* W   = (const float*)d_in[2];   // [4096][4096]
    const float* qa  = (const float*)d_in[3];   // [4][8][4096]
    const float* qb  = (const float*)d_in[4];   // [4][4096][8]
    const float* sc  = (const float*)d_in[5];   // [4096]
    float* out = (float*)d_out;                 // [8192][4096]

    unsigned short* Wp = (unsigned short*)d_ws;                 // [4096][4128]
    unsigned short* Xp = Wp + (size_t)4096 * KPRIME;            // [8192][4128]

    build_w<<<4096, 256, 0, stream>>>(W, qb, sc, Wp);
    conv_x<<<16384, 256, 0, stream>>>(x, Xp);
    calc_a<<<512, 256, 0, stream>>>(x, qa, tkw, Xp);
    gemm_k<<<2048, 256, 0, stream>>>(Xp, Wp, out);
}